// Round 2
// baseline (98.043 us; speedup 1.0000x reference)
//
#include <hip/hip_runtime.h>

// ParametrisedPooling: out[t] = sum_k w[n,k] * x_in[idx[n,k], :], n = indices_target[t]
// N6 = 163830 coarse nodes with 6 neighbors, N7 = 12 with 7 neighbors, D = 128.
//
// Memory-bound random gather. Key idea this round: non-temporal (nt) accesses
// for all single-use streams (output store, indices, weights, target) so the
// L2/L3 capacity is reserved for the x_in gather working set (335.6 MB table,
// ~1.5x average row reuse, slightly exceeding 256 MB L3).

constexpr int N6     = 163830;
constexpr int N7     = 12;
constexpr int N_OUT  = N6 + N7;   // 163842
constexpr int D      = 128;
constexpr int LANES_PER_ROW = 32;          // 32 lanes x float4 = 128 floats
constexpr int BLOCK  = 256;
constexpr int ROWS_PER_BLOCK = BLOCK / LANES_PER_ROW;  // 8

__global__ __launch_bounds__(BLOCK) void pooling_kernel(
    const float* __restrict__ x_in,      // [N_SRC, D]
    const float* __restrict__ w6,        // [N6, 6]
    const float* __restrict__ w7,        // [N7, 7]
    const int*   __restrict__ idx6,      // [N6, 6]
    const int*   __restrict__ idx7,      // [N7, 7]
    const int*   __restrict__ tgt,       // [N_OUT]
    float*       __restrict__ out)       // [N_OUT, D]
{
    const int row  = blockIdx.x * ROWS_PER_BLOCK + (threadIdx.x >> 5);
    const int lane = threadIdx.x & 31;
    if (row >= N_OUT) return;

    const int n = __builtin_nontemporal_load(tgt + row);

    float4 acc = make_float4(0.f, 0.f, 0.f, 0.f);

    if (n < N6) {
        const int*   ip = idx6 + (size_t)n * 6;
        const float* wp = w6   + (size_t)n * 6;
        int   src[6];
        float w[6];
#pragma unroll
        for (int k = 0; k < 6; ++k) {
            src[k] = __builtin_nontemporal_load(ip + k);
            w[k]   = __builtin_nontemporal_load(wp + k);
        }
#pragma unroll
        for (int k = 0; k < 6; ++k) {
            const float4 v = *reinterpret_cast<const float4*>(
                x_in + (size_t)src[k] * D + (size_t)lane * 4);
            acc.x += w[k] * v.x;
            acc.y += w[k] * v.y;
            acc.z += w[k] * v.z;
            acc.w += w[k] * v.w;
        }
    } else {
        const int m = n - N6;
        const int*   ip = idx7 + (size_t)m * 7;
        const float* wp = w7   + (size_t)m * 7;
#pragma unroll
        for (int k = 0; k < 7; ++k) {
            const int   s = __builtin_nontemporal_load(ip + k);
            const float w = __builtin_nontemporal_load(wp + k);
            const float4 v = *reinterpret_cast<const float4*>(
                x_in + (size_t)s * D + (size_t)lane * 4);
            acc.x += w * v.x;
            acc.y += w * v.y;
            acc.z += w * v.z;
            acc.w += w * v.w;
        }
    }

    float* op = out + (size_t)row * D + (size_t)lane * 4;
    __builtin_nontemporal_store(acc.x, op + 0);
    __builtin_nontemporal_store(acc.y, op + 1);
    __builtin_nontemporal_store(acc.z, op + 2);
    __builtin_nontemporal_store(acc.w, op + 3);
}

extern "C" void kernel_launch(void* const* d_in, const int* in_sizes, int n_in,
                              void* d_out, int out_size, void* d_ws, size_t ws_size,
                              hipStream_t stream) {
    const float* x_in = (const float*)d_in[0];
    const float* w6   = (const float*)d_in[1];
    const float* w7   = (const float*)d_in[2];
    const int*   idx6 = (const int*)d_in[3];
    const int*   idx7 = (const int*)d_in[4];
    const int*   tgt  = (const int*)d_in[5];
    float*       out  = (float*)d_out;

    const int grid = (N_OUT + ROWS_PER_BLOCK - 1) / ROWS_PER_BLOCK;
    pooling_kernel<<<grid, BLOCK, 0, stream>>>(x_in, w6, w7, idx6, idx7, tgt, out);
}

// Round 3
// 92.348 us; speedup vs baseline: 1.0617x; 1.0617x over previous
//
#include <hip/hip_runtime.h>

// ParametrisedPooling: out[t] = sum_k w[n,k] * x_in[idx[n,k], :], n = indices_target[t]
// N6 = 163830 coarse nodes with 6 neighbors, N7 = 12 with 7 neighbors, D = 128.
//
// Memory-bound random gather. R2 post-mortem: nt loads on idx/weights regressed
// (broadcast-reused lines need caching). This round: plain loads everywhere,
// nt ONLY on output stores (output is write-once, never read — don't let its
// 84 MB write-allocate evict the 335 MB gather table from L2/L3).

constexpr int N6     = 163830;
constexpr int N7     = 12;
constexpr int N_OUT  = N6 + N7;   // 163842
constexpr int D      = 128;
constexpr int LANES_PER_ROW = 32;          // 32 lanes x float4 = 128 floats
constexpr int BLOCK  = 256;
constexpr int ROWS_PER_BLOCK = BLOCK / LANES_PER_ROW;  // 8

__global__ __launch_bounds__(BLOCK) void pooling_kernel(
    const float* __restrict__ x_in,      // [N_SRC, D]
    const float* __restrict__ w6,        // [N6, 6]
    const float* __restrict__ w7,        // [N7, 7]
    const int*   __restrict__ idx6,      // [N6, 6]
    const int*   __restrict__ idx7,      // [N7, 7]
    const int*   __restrict__ tgt,       // [N_OUT]
    float*       __restrict__ out)       // [N_OUT, D]
{
    const int row  = blockIdx.x * ROWS_PER_BLOCK + (threadIdx.x >> 5);
    const int lane = threadIdx.x & 31;
    if (row >= N_OUT) return;

    const int n = tgt[row];

    float4 acc = make_float4(0.f, 0.f, 0.f, 0.f);

    if (n < N6) {
        const int*   ip = idx6 + (size_t)n * 6;
        const float* wp = w6   + (size_t)n * 6;
#pragma unroll
        for (int k = 0; k < 6; ++k) {
            const int   src = ip[k];
            const float w   = wp[k];
            const float4 v  = *reinterpret_cast<const float4*>(
                x_in + (size_t)src * D + (size_t)lane * 4);
            acc.x += w * v.x;
            acc.y += w * v.y;
            acc.z += w * v.z;
            acc.w += w * v.w;
        }
    } else {
        const int m = n - N6;
        const int*   ip = idx7 + (size_t)m * 7;
        const float* wp = w7   + (size_t)m * 7;
#pragma unroll
        for (int k = 0; k < 7; ++k) {
            const int   src = ip[k];
            const float w   = wp[k];
            const float4 v  = *reinterpret_cast<const float4*>(
                x_in + (size_t)src * D + (size_t)lane * 4);
            acc.x += w * v.x;
            acc.y += w * v.y;
            acc.z += w * v.z;
            acc.w += w * v.w;
        }
    }

    float* op = out + (size_t)row * D + (size_t)lane * 4;
    __builtin_nontemporal_store(acc.x, op + 0);
    __builtin_nontemporal_store(acc.y, op + 1);
    __builtin_nontemporal_store(acc.z, op + 2);
    __builtin_nontemporal_store(acc.w, op + 3);
}

extern "C" void kernel_launch(void* const* d_in, const int* in_sizes, int n_in,
                              void* d_out, int out_size, void* d_ws, size_t ws_size,
                              hipStream_t stream) {
    const float* x_in = (const float*)d_in[0];
    const float* w6   = (const float*)d_in[1];
    const float* w7   = (const float*)d_in[2];
    const int*   idx6 = (const int*)d_in[3];
    const int*   idx7 = (const int*)d_in[4];
    const int*   tgt  = (const int*)d_in[5];
    float*       out  = (float*)d_out;

    const int grid = (N_OUT + ROWS_PER_BLOCK - 1) / ROWS_PER_BLOCK;
    pooling_kernel<<<grid, BLOCK, 0, stream>>>(x_in, w6, w7, idx6, idx7, tgt, out);
}